// Round 9
// baseline (35.646 us; speedup 1.0000x reference)
//
#include <hip/hip_runtime.h>

#define NB   4
#define CIN  32
#define HH   56
#define WW   56
#define GIN  8
#define GOUT 8
#define LIN  4
#define LOUT 8
#define KK   9
#define HW   (HH * WW)        // 3136
#define PIXTOT (NB * HW)      // 12544
#define PPB  32               // pixels per block (256 thr = 32 pix * 8 g)
#define WSLICE (GIN * KK * LIN * LOUT)  // 2304 floats per c
#define WS_G 292              // padded per-g LDS stride -> conflict-free float4 reads
#define HP   58               // padded spatial dim
#define WP   58

typedef float v2f __attribute__((ext_vector_type(2)));
typedef float v4f __attribute__((ext_vector_type(4)));

// CDNA packed fp32 (dual-issue): compiler won't emit these from scalar IR; force them.
static __device__ __forceinline__ v2f pk_fma(v2f a, v2f b, v2f c) {
    v2f d;
    asm("v_pk_fma_f32 %0, %1, %2, %3" : "=v"(d) : "v"(a), "v"(b), "v"(c));
    return d;
}
static __device__ __forceinline__ v2f pk_add(v2f a, v2f b) {
    v2f d;
    asm("v_pk_add_f32 %0, %1, %2" : "=v"(d) : "v"(a), "v"(b));
    return d;
}
static __device__ __forceinline__ v2f pk_mul(v2f a, v2f b) {
    v2f d;
    asm("v_pk_mul_f32 %0, %1, %2" : "=v"(d) : "v"(a), "v"(b));
    return d;
}

// ---- pre-pass: x[n][ch][h][w] -> xt[n][hp][wp][ch] with zero border ----
__global__ __launch_bounds__(256) void transpose_x_kernel(
    const float* __restrict__ x, float* __restrict__ xt)
{
    __shared__ float tile[CIN * 57];     // 57 stride: conflict-free transposed read
    const int b = blockIdx.x;            // n*HP + hp
    const int n = b / HP;
    const int hp = b - n * HP;
    const int h = hp - 1;
    const int tid = threadIdx.x;
    const bool rowok = (unsigned)h < (unsigned)HH;

    if (rowok) {
        for (int i = tid; i < CIN * WW; i += 256) {
            const int ch = i / WW;
            const int w  = i - ch * WW;  // lanes: w consecutive -> coalesced read
            tile[ch * 57 + w] = x[((n * CIN + ch) * HH + h) * WW + w];
        }
    }
    __syncthreads();
    float* dst = xt + ((size_t)(n * HP + hp) * WP) * CIN;
    for (int i = tid; i < WP * CIN; i += 256) {
        const int wp = i >> 5;
        const int ch = i & 31;           // lanes: ch consecutive -> coalesced write
        const bool ok = rowok && (wp >= 1) && (wp <= WW);
        dst[i] = ok ? tile[ch * 57 + (wp - 1)] : 0.0f;
    }
}

__global__ __launch_bounds__(256) void caps_routing_kernel(
    const float* __restrict__ xt, const float* __restrict__ wt,
    float* __restrict__ out)
{
    __shared__ __align__(16) float ws[GIN * WS_G];   // 9344 B

    const int tid = threadIdx.x;
    const int c = blockIdx.y;

    const int g  = tid & 7;
    const int pl = tid >> 3;
    const int pix = blockIdx.x * PPB + pl;   // 392*32 == 12544 exactly
    const int n = pix / HW;
    const int p = pix - n * HW;
    const int h = p / WW;
    const int w = p - h * WW;

    // ---- x-gather: 9 unconditional float4 loads from the padded layout ----
    v4f xv4[KK];
    const float* base = xt + ((size_t)((n * HP + h) * WP + w)) * CIN + g * 4;
    #pragma unroll
    for (int ki = 0; ki < 3; ++ki)
        #pragma unroll
        for (int kj = 0; kj < 3; ++kj)
            xv4[ki * 3 + kj] =
                *reinterpret_cast<const v4f*>(base + (ki * WP + kj) * CIN);

    // ---- stage this c's weight slice: [g][k][l][m], per-g padded to 292 ----
    {
        const int gg = tid >> 5;
        const int r0 = tid & 31;
        const float* src = wt + c * WSLICE + gg * 288;
        float* dst = ws + gg * WS_G;
        #pragma unroll
        for (int j = 0; j < 9; ++j)
            dst[r0 + j * 32] = src[r0 + j * 32];
    }
    __syncthreads();

    // ---- priors (packed pairs): pr2[k][j] = m-pair j of prior vector k ----
    v2f pr2[KK][4];
    v2f ks2[4] = {v2f{0.f,0.f}, v2f{0.f,0.f}, v2f{0.f,0.f}, v2f{0.f,0.f}};

    const float* wg = &ws[g * WS_G];
    #pragma unroll
    for (int k = 0; k < KK; ++k) {
        v2f a0 = {0.f,0.f}, a1 = {0.f,0.f}, a2 = {0.f,0.f}, a3 = {0.f,0.f};
        #pragma unroll
        for (int l = 0; l < LIN; ++l) {
            const float xs = xv4[k][l];
            const v2f xs2 = {xs, xs};
            const v4f w01 = *reinterpret_cast<const v4f*>(wg + k * 32 + l * 8);
            const v4f w23 = *reinterpret_cast<const v4f*>(wg + k * 32 + l * 8 + 4);
            a0 = pk_fma(xs2, __builtin_shufflevector(w01, w01, 0, 1), a0);
            a1 = pk_fma(xs2, __builtin_shufflevector(w01, w01, 2, 3), a1);
            a2 = pk_fma(xs2, __builtin_shufflevector(w23, w23, 0, 1), a2);
            a3 = pk_fma(xs2, __builtin_shufflevector(w23, w23, 2, 3), a3);
        }
        pr2[k][0] = a0; pr2[k][1] = a1; pr2[k][2] = a2; pr2[k][3] = a3;
        ks2[0] = pk_add(ks2[0], a0); ks2[1] = pk_add(ks2[1], a1);
        ks2[2] = pk_add(ks2[2], a2); ks2[3] = pk_add(ks2[3], a3);
    }

    // ---- dynamic routing, ITERS = 3 ----
    float logits[KK];
    #pragma unroll
    for (int k = 0; k < KK; ++k) logits[k] = 0.0f;

    v2f v2[4];
    #pragma unroll
    for (int it = 0; it < 3; ++it) {
        v2f s2[4];
        if (it == 0) {
            const v2f ninth = {1.0f / 9.0f, 1.0f / 9.0f};
            #pragma unroll
            for (int j = 0; j < 4; ++j) s2[j] = pk_mul(ks2[j], ninth);
        } else {
            // softmax without max-subtraction (|logits| small); 1/sum folded in
            float e[KK];
            float sum = 0.0f;
            #pragma unroll
            for (int k = 0; k < KK; ++k) { e[k] = __expf(logits[k]); sum += e[k]; }
            const float inv = 1.0f / sum;
            #pragma unroll
            for (int j = 0; j < 4; ++j) s2[j] = v2f{0.f, 0.f};
            #pragma unroll
            for (int k = 0; k < KK; ++k) {
                const v2f ek = {e[k], e[k]};
                #pragma unroll
                for (int j = 0; j < 4; ++j) s2[j] = pk_fma(ek, pr2[k][j], s2[j]);
            }
            const v2f inv2 = {inv, inv};
            #pragma unroll
            for (int j = 0; j < 4; ++j) s2[j] = pk_mul(s2[j], inv2);
        }

        // reduce partial s over the 8 g-lanes (in-wave butterfly)
        #pragma unroll
        for (int off = 1; off < 8; off <<= 1) {
            #pragma unroll
            for (int j = 0; j < 4; ++j) {
                s2[j].x += __shfl_xor(s2[j].x, off, 64);
                s2[j].y += __shfl_xor(s2[j].y, off, 64);
            }
        }

        // squash: v = (|s| / (1 + |s|^2)) * s
        v2f t = pk_mul(s2[0], s2[0]);
        t = pk_fma(s2[1], s2[1], t);
        t = pk_fma(s2[2], s2[2], t);
        t = pk_fma(s2[3], s2[3], t);
        const float n2 = t.x + t.y;
        const float f = sqrtf(n2) / (1.0f + n2);
        const v2f f2 = {f, f};
        #pragma unroll
        for (int j = 0; j < 4; ++j) v2[j] = pk_mul(f2, s2[j]);

        if (it != 2) {
            #pragma unroll
            for (int k = 0; k < KK; ++k) {
                v2f d2 = pk_mul(pr2[k][0], v2[0]);
                d2 = pk_fma(pr2[k][1], v2[1], d2);
                d2 = pk_fma(pr2[k][2], v2[2], d2);
                d2 = pk_fma(pr2[k][3], v2[3], d2);
                logits[k] += d2.x + d2.y;
            }
        }
    }

    // lane (pl, g) writes output component m = g (static select chain)
    const float vs[8] = { v2[0].x, v2[0].y, v2[1].x, v2[1].y,
                          v2[2].x, v2[2].y, v2[3].x, v2[3].y };
    float outv = vs[0];
    #pragma unroll
    for (int m = 1; m < LOUT; ++m) if (g == m) outv = vs[m];
    out[(n * GOUT * LOUT + c * LOUT + g) * HW + p] = outv;
}

extern "C" void kernel_launch(void* const* d_in, const int* in_sizes, int n_in,
                              void* d_out, int out_size, void* d_ws, size_t ws_size,
                              hipStream_t stream) {
    const float* x  = (const float*)d_in[0];
    const float* wt = (const float*)d_in[1];
    float* out = (float*)d_out;
    float* xt = (float*)d_ws;   // 4*58*58*32 floats = 1.72 MB scratch

    transpose_x_kernel<<<dim3(NB * HP), dim3(256), 0, stream>>>(x, xt);
    dim3 grid(PIXTOT / PPB, GOUT);   // 392 x 8
    caps_routing_kernel<<<grid, dim3(256), 0, stream>>>(xt, wt, out);
}